// Round 7
// baseline (91.384 us; speedup 1.0000x reference)
//
#include <hip/hip_runtime.h>
#include <hip/hip_bf16.h>

#define B_ 4
#define N_ 4096
#define D_ 128
#define EPB (N_ * D_)        // BYTES per batch in packed fp8 layout = 524288
#define COFF 1024.0f         // colmin positivity offset

typedef float f32x4 __attribute__((ext_vector_type(4)));
typedef int   int8v __attribute__((ext_vector_type(8)));
typedef int   int4v __attribute__((ext_vector_type(4)));

#define SQRT2 1.41421356237309515f

// ---------------------------------------------------------------------------
// Packed K-major fp8 layout (per batch, BYTE addresses):
//   elem(row, k) -> (row>>4)*2048 + (k>>5)*512 + (row&15)*32 + (k&31)
// K=128 MFMA fragment (16x16x128 f8f6f4): lane (quad,l16): row = l16,
// k = quad*32 + j  ->  32 CONTIGUOUS bytes at rg*2048 + quad*512 + l16*32.
// REGISTER CLIFF LOG (updated):
//   R13: computed-value acc init -> spill. RULE: acc inline-ZERO init only
//        (keeps accumulator in AGPR half; arch stays ~128).
//   R15: rotation + FULL-UNROLL s-loop -> spill 80MB. Re-audit: the unroll
//        pragma let the scheduler hoist all 4 steps' prefetches -> liveness
//        blowup. Depth-1 prefetch in a ROLLED loop was never tested.
//   R14/R16: more blocks / more waves both ~flat => occupancy NOT binding.
//        Residual theory: per-substep load latency serially exposed.
// R17: 8 substeps x 32 cols, acc[4][2] (32 AGPR zero-init), depth-1 reg
// double-buffer (named bA*/bB*, rolled sp-loop, 2 bodies/iter):
//   body = { PREF(next); MFMA(cur); FOLD(cur) }  -- cur's loads issued one
// body earlier, hidden under ~450cyc of MFMA+fold. Unified regs ~146.
// ---------------------------------------------------------------------------

// Kernel 1: fp32 -> fp8 e4m3 (*sqrt2) into packed layout + row norms + min
// init. Thread t: row r = t>>4 (in group), k-chunk c = t&15 -> consecutive
// lanes read consecutive 32 B (fully coalesced). Norm: 4 in-group shuffles.
__global__ __launch_bounds__(256) void prep_kernel(
    const float* __restrict__ X, const float* __restrict__ Y,
    unsigned char* __restrict__ Xb, unsigned char* __restrict__ Yb,
    float* __restrict__ x2, float* __restrict__ y2,
    int* __restrict__ rowmin, int* __restrict__ colmin)
{
    const int which = blockIdx.y;
    const float* __restrict__ src = which ? Y : X;
    unsigned char* __restrict__ dst = which ? Yb : Xb;
    float* __restrict__ nrm = which ? y2 : x2;
    int* __restrict__ mn = which ? colmin : rowmin;

    const int t = threadIdx.x;
    const int r = t >> 4, c = t & 15;          // r,c in 0..15
    const int rgG = blockIdx.x;                // global row-group
    const int row = rgG * 16 + r;

    const float4 v0 = *(const float4*)(src + (size_t)row * D_ + c * 8);
    const float4 v1 = *(const float4*)(src + (size_t)row * D_ + c * 8 + 4);

    float sq = v0.x * v0.x;
    sq = fmaf(v0.y, v0.y, sq); sq = fmaf(v0.z, v0.z, sq); sq = fmaf(v0.w, v0.w, sq);
    sq = fmaf(v1.x, v1.x, sq); sq = fmaf(v1.y, v1.y, sq);
    sq = fmaf(v1.z, v1.z, sq); sq = fmaf(v1.w, v1.w, sq);
    // reduce across the 16 lanes of this row (xor masks stay in-group)
    #pragma unroll
    for (int m = 1; m < 16; m <<= 1) sq += __shfl_xor(sq, m);

    unsigned lo = 0, hi = 0;
    lo = __builtin_amdgcn_cvt_pk_fp8_f32(v0.x * SQRT2, v0.y * SQRT2, lo, false);
    lo = __builtin_amdgcn_cvt_pk_fp8_f32(v0.z * SQRT2, v0.w * SQRT2, lo, true);
    hi = __builtin_amdgcn_cvt_pk_fp8_f32(v1.x * SQRT2, v1.y * SQRT2, hi, false);
    hi = __builtin_amdgcn_cvt_pk_fp8_f32(v1.z * SQRT2, v1.w * SQRT2, hi, true);

    const int b = row >> 12;
    const int rg = (row & (N_ - 1)) >> 4;
    uint2 packed; packed.x = lo; packed.y = hi;
    // k = c*8:  (k>>5) = c>>2,  (k&31) = (c&3)*8
    *(uint2*)(dst + (size_t)b * EPB + rg * 2048 + (c >> 2) * 512
              + r * 32 + (c & 3) * 8) = packed;

    if (c == 0) {
        nrm[row] = sq;
        mn[row] = 0x7f7fffff;   // +FLT_MAX bits
    }
}

// ---------------------------------------------------------------------------
// Kernel 2: stripe-sweep MX-fp8 (K=128) MFMA chamfer. NO LDS, NO barriers.
// Block = 4 waves x 64 distinct rows = 256-row stripe (grid y = 16).
// jc = 256-col chunk (grid x = 16); 8 substeps x 32 cols, depth-1 reg
// double-buffer. acc ZERO-INIT only (AGPR rule). Fold (R10 style):
//   rm = min(rm, y2 - acc);  cm = min(cm, x2 - acc).
//   C/D layout: row = quad*4 + reg, col = l16   [m89; shape-determined]
// ---------------------------------------------------------------------------

// prefetch substep H's 2 B-fragments + 2 y2 values into named regs
#define PREF(B0, B1, Y0, Y1, H) do {                                          \
    const int cb_ = jc * 256 + (H) * 32;                                      \
    const unsigned char* bp0_ = Yp + (size_t)(cb_ >> 4) * 2048                \
                               + quad * 512 + l16 * 32;                       \
    const int4v lo0_ = *(const int4v*)(bp0_);                                 \
    const int4v hi0_ = *(const int4v*)(bp0_ + 16);                            \
    const int4v lo1_ = *(const int4v*)(bp0_ + 2048);                          \
    const int4v hi1_ = *(const int4v*)(bp0_ + 2064);                          \
    B0 = (int8v){lo0_.x, lo0_.y, lo0_.z, lo0_.w, hi0_.x, hi0_.y, hi0_.z, hi0_.w}; \
    B1 = (int8v){lo1_.x, lo1_.y, lo1_.z, lo1_.w, hi1_.x, hi1_.y, hi1_.z, hi1_.w}; \
    Y0 = y2[(size_t)b * N_ + cb_ + l16];                                      \
    Y1 = y2[(size_t)b * N_ + cb_ + 16 + l16];                                 \
} while (0)

// 8 MFMAs + fold for substep H using named buffers
#define STEP(B0, B1, Y0, Y1, H) do {                                          \
    f32x4 acc0_[4], acc1_[4];                                                 \
    _Pragma("unroll")                                                         \
    for (int rt = 0; rt < 4; rt++) {                                          \
        acc0_[rt] = (f32x4){0.f, 0.f, 0.f, 0.f};                              \
        acc1_[rt] = (f32x4){0.f, 0.f, 0.f, 0.f};                              \
    }                                                                         \
    _Pragma("unroll")                                                         \
    for (int rt = 0; rt < 4; rt++) {                                          \
        acc0_[rt] = __builtin_amdgcn_mfma_scale_f32_16x16x128_f8f6f4(         \
            af[rt], B0, acc0_[rt], 0, 0, 0, 127, 0, 127);                     \
        acc1_[rt] = __builtin_amdgcn_mfma_scale_f32_16x16x128_f8f6f4(         \
            af[rt], B1, acc1_[rt], 0, 0, 0, 127, 0, 127);                     \
    }                                                                         \
    float cm0_ = 3.0e38f, cm1_ = 3.0e38f;                                     \
    _Pragma("unroll")                                                         \
    for (int rt = 0; rt < 4; rt++)                                            \
    _Pragma("unroll")                                                         \
    for (int i = 0; i < 4; i++) {                                             \
        const float xv_ = x2v[rt][i];                                         \
        const float a0_ = acc0_[rt][i], a1_ = acc1_[rt][i];                   \
        rmin[rt][i] = fminf(rmin[rt][i], fminf(Y0 - a0_, Y1 - a1_));          \
        cm0_ = fminf(cm0_, xv_ - a0_);                                        \
        cm1_ = fminf(cm1_, xv_ - a1_);                                        \
    }                                                                         \
    {                                                                         \
        const int cb_ = jc * 256 + (H) * 32;                                  \
        float v0_ = fminf(cm0_, __shfl_xor(cm0_, 16));                        \
        v0_ = fminf(v0_, __shfl_xor(v0_, 32));                                \
        float v1_ = fminf(cm1_, __shfl_xor(cm1_, 16));                        \
        v1_ = fminf(v1_, __shfl_xor(v1_, 32));                                \
        if (quad == 0) {                                                      \
            atomicMin(&colmin[(size_t)b * N_ + cb_ + l16],                    \
                      __float_as_int(v0_ + COFF));                            \
            atomicMin(&colmin[(size_t)b * N_ + cb_ + 16 + l16],               \
                      __float_as_int(v1_ + COFF));                            \
        }                                                                     \
    }                                                                         \
} while (0)

__global__ __launch_bounds__(256, 2) void chamfer_mfma(
    const unsigned char* __restrict__ Xb, const unsigned char* __restrict__ Yb,
    const float* __restrict__ x2, const float* __restrict__ y2,
    int* __restrict__ rowmin, int* __restrict__ colmin)
{
    const int b = blockIdx.z;
    const int iT = blockIdx.y;           // 0..15  (256-row stripe)
    const int jc = blockIdx.x;           // 0..15  (256-col chunk)
    const int tid = threadIdx.x;
    const int wave = tid >> 6, lane = tid & 63;
    const int quad = lane >> 4, l16 = lane & 15;
    const int rowBase = iT * 256 + wave * 64;

    const unsigned char* __restrict__ Xp = Xb + (size_t)b * EPB;
    const unsigned char* __restrict__ Yp = Yb + (size_t)b * EPB;

    // ---- A fragments resident (4 x v8i32 = 32 VGPR), register-only build ----
    int8v af[4];
    #pragma unroll
    for (int rt = 0; rt < 4; rt++) {
        const unsigned char* ap = Xp + ((rowBase >> 4) + rt) * 2048
                                 + quad * 512 + l16 * 32;
        const int4v lo = *(const int4v*)(ap);
        const int4v hi = *(const int4v*)(ap + 16);
        af[rt] = (int8v){lo.x, lo.y, lo.z, lo.w, hi.x, hi.y, hi.z, hi.w};
    }
    // row = rowBase + rt*16 + quad*4 + i -> one aligned float4 per rt
    f32x4 x2v[4];
    #pragma unroll
    for (int rt = 0; rt < 4; rt++)
        x2v[rt] = *(const f32x4*)(x2 + (size_t)b * N_ + rowBase + rt * 16 + quad * 4);

    float rmin[4][4];
    #pragma unroll
    for (int rt = 0; rt < 4; rt++)
        #pragma unroll
        for (int i = 0; i < 4; i++) rmin[rt][i] = 3.0e38f;

    // ---- depth-1 double-buffered substep pipeline (8 substeps) ----
    int8v bA0, bA1, bB0, bB1;
    float yA0, yA1, yB0, yB1;
    PREF(bA0, bA1, yA0, yA1, 0);

    #pragma clang loop unroll(disable)
    for (int sp = 0; sp < 4; ++sp) {
        const int h0 = sp * 2;
        PREF(bB0, bB1, yB0, yB1, h0 + 1);   // lands under STEP(h0)
        STEP(bA0, bA1, yA0, yA1, h0);
        if (sp < 3)
            PREF(bA0, bA1, yA0, yA1, h0 + 2);  // lands under STEP(h0+1)
        STEP(bB0, bB1, yB0, yB1, h0 + 1);
    }

    // ---- rowmin emission (once per block) ----
    #pragma unroll
    for (int rt = 0; rt < 4; rt++)
        #pragma unroll
        for (int i = 0; i < 4; i++) {
            float v = rmin[rt][i];
            #pragma unroll
            for (int m = 1; m < 16; m <<= 1) v = fminf(v, __shfl_xor(v, m));
            if (l16 == 0) {
                float c = fminf(fmaxf(x2v[rt][i] + v, 0.0f), 100.0f);
                atomicMin(&rowmin[(size_t)b * N_ + rowBase + rt * 16 + quad * 4 + i],
                          __float_as_int(c));
            }
        }
}

// ---------------------------------------------------------------------------
// Kernel 3a: partial sums, 16 blocks x 256 threads, one int4-group each.
// rowmin holds clamped values; colmin holds (min_i(x2_i - acc) + COFF):
// add y2, subtract COFF, clamp here. Deterministic tree order.
// ---------------------------------------------------------------------------
__global__ __launch_bounds__(256) void finalize1_kernel(
    const int* __restrict__ rowmin, const int* __restrict__ colmin,
    const float* __restrict__ y2, float* __restrict__ partial)
{
    const int i = blockIdx.x * 256 + threadIdx.x;   // 0..4095 int4-groups
    float s;
    {
        int4 v = ((const int4*)rowmin)[i];
        s  = __int_as_float(v.x) + __int_as_float(v.y) +
             __int_as_float(v.z) + __int_as_float(v.w);
        int4 c = ((const int4*)colmin)[i];
        float4 yv = ((const float4*)y2)[i];
        s += fminf(fmaxf(__int_as_float(c.x) - COFF + yv.x, 0.f), 100.f);
        s += fminf(fmaxf(__int_as_float(c.y) - COFF + yv.y, 0.f), 100.f);
        s += fminf(fmaxf(__int_as_float(c.z) - COFF + yv.z, 0.f), 100.f);
        s += fminf(fmaxf(__int_as_float(c.w) - COFF + yv.w, 0.f), 100.f);
    }
    #pragma unroll
    for (int m = 1; m < 64; m <<= 1) s += __shfl_xor(s, m);
    __shared__ float sm[4];
    if ((threadIdx.x & 63) == 0) sm[threadIdx.x >> 6] = s;
    __syncthreads();
    if (threadIdx.x == 0)
        partial[blockIdx.x] = sm[0] + sm[1] + sm[2] + sm[3];
}

// Kernel 3b: one wave folds the 16 partials.
__global__ __launch_bounds__(64) void finalize2_kernel(
    const float* __restrict__ partial, float* __restrict__ out)
{
    const int l = threadIdx.x;
    float s = (l < 16) ? partial[l] : 0.f;
    #pragma unroll
    for (int m = 1; m < 16; m <<= 1) s += __shfl_xor(s, m);
    if (l == 0)
        out[0] = s / ((float)B_ * (float)N_) / (float)B_;
}

extern "C" void kernel_launch(void* const* d_in, const int* in_sizes, int n_in,
                              void* d_out, int out_size, void* d_ws, size_t ws_size,
                              hipStream_t stream) {
    const float* X = (const float*)d_in[0];   // corr_pred   [B,N,D] fp32
    const float* Y = (const float*)d_in[1];   // corr_target [B,N,D] fp32

    char* ws = (char*)d_ws;
    const size_t f8_bytes = (size_t)B_ * N_ * D_;       // 2 MB each (packed fp8)
    unsigned char* Xb = (unsigned char*)ws;
    unsigned char* Yb = (unsigned char*)(ws + f8_bytes);
    char* ws2 = ws + 2 * f8_bytes;
    const size_t vec_bytes = (size_t)B_ * N_ * 4;       // 64 KB each
    float* x2      = (float*)(ws2);
    float* y2      = (float*)(ws2 + vec_bytes);
    int*   rowmin  = (int*)  (ws2 + 2 * vec_bytes);
    int*   colmin  = (int*)  (ws2 + 3 * vec_bytes);
    float* partial = (float*)(ws2 + 4 * vec_bytes);     // 16 floats
    float* out = (float*)d_out;

    prep_kernel<<<dim3(B_ * N_ / 16, 2), 256, 0, stream>>>(
        X, Y, Xb, Yb, x2, y2, rowmin, colmin);
    chamfer_mfma<<<dim3(16, N_ / 256, B_), 256, 0, stream>>>(
        Xb, Yb, x2, y2, rowmin, colmin);
    finalize1_kernel<<<16, 256, 0, stream>>>(rowmin, colmin, y2, partial);
    finalize2_kernel<<<1, 64, 0, stream>>>(partial, out);
}

// Round 8
// 90.807 us; speedup vs baseline: 1.0064x; 1.0064x over previous
//
#include <hip/hip_runtime.h>
#include <hip/hip_bf16.h>

#define B_ 4
#define N_ 4096
#define D_ 128
#define EPB (N_ * D_)        // BYTES per batch in packed fp8 layout = 524288

typedef float f32x4 __attribute__((ext_vector_type(4)));
typedef int   int8v __attribute__((ext_vector_type(8)));
typedef int   int4v __attribute__((ext_vector_type(4)));

#define SQRT2 1.41421356237309515f

// ---------------------------------------------------------------------------
// Packed K-major fp8 layout (per batch, BYTE addresses):
//   elem(row, k) -> (row>>4)*2048 + (k>>5)*512 + (row&15)*32 + (k&31)
// K=128 MFMA fragment (16x16x128 f8f6f4): lane (quad,l16): row = l16,
// k = quad*32 + j  ->  32 CONTIGUOUS bytes at rg*2048 + quad*512 + l16*32.
// REGISTER CLIFF LOG:
//   R13: computed-value acc init -> spill. RULE: acc inline-ZERO init only
//        (keeps accumulator in AGPR half; arch stays ~128).
//   R15: rotation + full-unroll s-loop -> spill (liveness blowup).
// THEORY LEDGER (chamfer ~38us vs ~7us issue floor):
//   occupancy NOT binding (R14 more blocks flat; R16 smaller acc flat).
//   load latency NOT binding (R17 depth-1 reg dbuf flat).
//   R18 hypothesis: ~1.05M device-scope atomicMin lane-ops serialize at the
//   memory-side coherence point (per-XCD L2s non-coherent) and entangle
//   with vmcnt around every substep. Eliminate ALL global atomics:
//   plain-store per-wave partials, reduce in finalize.
//     cpart[b][iT*4+wave][col] = min over wave's 64 rows of (x2 - acc)
//     rpart[b][jc][row]        = clamp(x2 + min over chunk cols of (y2-acc))
//   (unique writer per element; clamp commutes with min: monotone.)
// ---------------------------------------------------------------------------

// Kernel 1: fp32 -> fp8 e4m3 (*sqrt2) into packed layout + row norms.
// Thread t: row r = t>>4 (in group), k-chunk c = t&15 -> consecutive
// lanes read consecutive 32 B (fully coalesced). Norm: 4 in-group shuffles.
__global__ __launch_bounds__(256) void prep_kernel(
    const float* __restrict__ X, const float* __restrict__ Y,
    unsigned char* __restrict__ Xb, unsigned char* __restrict__ Yb,
    float* __restrict__ x2, float* __restrict__ y2)
{
    const int which = blockIdx.y;
    const float* __restrict__ src = which ? Y : X;
    unsigned char* __restrict__ dst = which ? Yb : Xb;
    float* __restrict__ nrm = which ? y2 : x2;

    const int t = threadIdx.x;
    const int r = t >> 4, c = t & 15;          // r,c in 0..15
    const int rgG = blockIdx.x;                // global row-group
    const int row = rgG * 16 + r;

    const float4 v0 = *(const float4*)(src + (size_t)row * D_ + c * 8);
    const float4 v1 = *(const float4*)(src + (size_t)row * D_ + c * 8 + 4);

    float sq = v0.x * v0.x;
    sq = fmaf(v0.y, v0.y, sq); sq = fmaf(v0.z, v0.z, sq); sq = fmaf(v0.w, v0.w, sq);
    sq = fmaf(v1.x, v1.x, sq); sq = fmaf(v1.y, v1.y, sq);
    sq = fmaf(v1.z, v1.z, sq); sq = fmaf(v1.w, v1.w, sq);
    // reduce across the 16 lanes of this row (xor masks stay in-group)
    #pragma unroll
    for (int m = 1; m < 16; m <<= 1) sq += __shfl_xor(sq, m);

    unsigned lo = 0, hi = 0;
    lo = __builtin_amdgcn_cvt_pk_fp8_f32(v0.x * SQRT2, v0.y * SQRT2, lo, false);
    lo = __builtin_amdgcn_cvt_pk_fp8_f32(v0.z * SQRT2, v0.w * SQRT2, lo, true);
    hi = __builtin_amdgcn_cvt_pk_fp8_f32(v1.x * SQRT2, v1.y * SQRT2, hi, false);
    hi = __builtin_amdgcn_cvt_pk_fp8_f32(v1.z * SQRT2, v1.w * SQRT2, hi, true);

    const int b = row >> 12;
    const int rg = (row & (N_ - 1)) >> 4;
    uint2 packed; packed.x = lo; packed.y = hi;
    // k = c*8:  (k>>5) = c>>2,  (k&31) = (c&3)*8
    *(uint2*)(dst + (size_t)b * EPB + rg * 2048 + (c >> 2) * 512
              + r * 32 + (c & 3) * 8) = packed;

    if (c == 0) nrm[row] = sq;
}

// ---------------------------------------------------------------------------
// Kernel 2: stripe-sweep MX-fp8 (K=128) MFMA chamfer. NO LDS, NO barriers,
// NO atomics. Block = 4 waves x 64 distinct rows = 256-row stripe (grid y=16).
// jc = 256-col chunk (grid x = 16); 8 substeps x 32 cols, depth-1 reg
// double-buffer (R17 pipeline). acc ZERO-INIT only (AGPR rule). Fold:
//   rm = min(rm, y2 - acc);  cm = min(cm, x2 - acc).
//   C/D layout: row = quad*4 + reg, col = l16   [m89; shape-determined]
// ---------------------------------------------------------------------------

// prefetch substep H's 2 B-fragments + 2 y2 values into named regs
#define PREF(B0, B1, Y0, Y1, H) do {                                          \
    const int cb_ = jc * 256 + (H) * 32;                                      \
    const unsigned char* bp0_ = Yp + (size_t)(cb_ >> 4) * 2048                \
                               + quad * 512 + l16 * 32;                       \
    const int4v lo0_ = *(const int4v*)(bp0_);                                 \
    const int4v hi0_ = *(const int4v*)(bp0_ + 16);                            \
    const int4v lo1_ = *(const int4v*)(bp0_ + 2048);                          \
    const int4v hi1_ = *(const int4v*)(bp0_ + 2064);                          \
    B0 = (int8v){lo0_.x, lo0_.y, lo0_.z, lo0_.w, hi0_.x, hi0_.y, hi0_.z, hi0_.w}; \
    B1 = (int8v){lo1_.x, lo1_.y, lo1_.z, lo1_.w, hi1_.x, hi1_.y, hi1_.z, hi1_.w}; \
    Y0 = y2[(size_t)b * N_ + cb_ + l16];                                      \
    Y1 = y2[(size_t)b * N_ + cb_ + 16 + l16];                                 \
} while (0)

// 8 MFMAs + fold for substep H using named buffers; col-min via plain store
#define STEP(B0, B1, Y0, Y1, H) do {                                          \
    f32x4 acc0_[4], acc1_[4];                                                 \
    _Pragma("unroll")                                                         \
    for (int rt = 0; rt < 4; rt++) {                                          \
        acc0_[rt] = (f32x4){0.f, 0.f, 0.f, 0.f};                              \
        acc1_[rt] = (f32x4){0.f, 0.f, 0.f, 0.f};                              \
    }                                                                         \
    _Pragma("unroll")                                                         \
    for (int rt = 0; rt < 4; rt++) {                                          \
        acc0_[rt] = __builtin_amdgcn_mfma_scale_f32_16x16x128_f8f6f4(         \
            af[rt], B0, acc0_[rt], 0, 0, 0, 127, 0, 127);                     \
        acc1_[rt] = __builtin_amdgcn_mfma_scale_f32_16x16x128_f8f6f4(         \
            af[rt], B1, acc1_[rt], 0, 0, 0, 127, 0, 127);                     \
    }                                                                         \
    float cm0_ = 3.0e38f, cm1_ = 3.0e38f;                                     \
    _Pragma("unroll")                                                         \
    for (int rt = 0; rt < 4; rt++)                                            \
    _Pragma("unroll")                                                         \
    for (int i = 0; i < 4; i++) {                                             \
        const float xv_ = x2v[rt][i];                                         \
        const float a0_ = acc0_[rt][i], a1_ = acc1_[rt][i];                   \
        rmin[rt][i] = fminf(rmin[rt][i], fminf(Y0 - a0_, Y1 - a1_));          \
        cm0_ = fminf(cm0_, xv_ - a0_);                                        \
        cm1_ = fminf(cm1_, xv_ - a1_);                                        \
    }                                                                         \
    {                                                                         \
        const int cb_ = jc * 256 + (H) * 32;                                  \
        float v0_ = fminf(cm0_, __shfl_xor(cm0_, 16));                        \
        v0_ = fminf(v0_, __shfl_xor(v0_, 32));                                \
        float v1_ = fminf(cm1_, __shfl_xor(cm1_, 16));                        \
        v1_ = fminf(v1_, __shfl_xor(v1_, 32));                                \
        if (quad == 0) {                                                      \
            cpart[cpb + cb_ + l16] = v0_;                                     \
            cpart[cpb + cb_ + 16 + l16] = v1_;                                \
        }                                                                     \
    }                                                                         \
} while (0)

__global__ __launch_bounds__(256, 2) void chamfer_mfma(
    const unsigned char* __restrict__ Xb, const unsigned char* __restrict__ Yb,
    const float* __restrict__ x2, const float* __restrict__ y2,
    float* __restrict__ rpart, float* __restrict__ cpart)
{
    const int b = blockIdx.z;
    const int iT = blockIdx.y;           // 0..15  (256-row stripe)
    const int jc = blockIdx.x;           // 0..15  (256-col chunk)
    const int tid = threadIdx.x;
    const int wave = tid >> 6, lane = tid & 63;
    const int quad = lane >> 4, l16 = lane & 15;
    const int rowBase = iT * 256 + wave * 64;
    // unique-writer partial bases
    const size_t cpb = (size_t)((b * 16 + iT) * 4 + wave) * N_;
    const size_t rpb = (size_t)(b * 16 + jc) * N_;

    const unsigned char* __restrict__ Xp = Xb + (size_t)b * EPB;
    const unsigned char* __restrict__ Yp = Yb + (size_t)b * EPB;

    // ---- A fragments resident (4 x v8i32 = 32 VGPR), register-only build ----
    int8v af[4];
    #pragma unroll
    for (int rt = 0; rt < 4; rt++) {
        const unsigned char* ap = Xp + ((rowBase >> 4) + rt) * 2048
                                 + quad * 512 + l16 * 32;
        const int4v lo = *(const int4v*)(ap);
        const int4v hi = *(const int4v*)(ap + 16);
        af[rt] = (int8v){lo.x, lo.y, lo.z, lo.w, hi.x, hi.y, hi.z, hi.w};
    }
    // row = rowBase + rt*16 + quad*4 + i -> one aligned float4 per rt
    f32x4 x2v[4];
    #pragma unroll
    for (int rt = 0; rt < 4; rt++)
        x2v[rt] = *(const f32x4*)(x2 + (size_t)b * N_ + rowBase + rt * 16 + quad * 4);

    float rmin[4][4];
    #pragma unroll
    for (int rt = 0; rt < 4; rt++)
        #pragma unroll
        for (int i = 0; i < 4; i++) rmin[rt][i] = 3.0e38f;

    // ---- depth-1 double-buffered substep pipeline (8 substeps) ----
    int8v bA0, bA1, bB0, bB1;
    float yA0, yA1, yB0, yB1;
    PREF(bA0, bA1, yA0, yA1, 0);

    #pragma clang loop unroll(disable)
    for (int sp = 0; sp < 4; ++sp) {
        const int h0 = sp * 2;
        PREF(bB0, bB1, yB0, yB1, h0 + 1);   // lands under STEP(h0)
        STEP(bA0, bA1, yA0, yA1, h0);
        if (sp < 3)
            PREF(bA0, bA1, yA0, yA1, h0 + 2);  // lands under STEP(h0+1)
        STEP(bB0, bB1, yB0, yB1, h0 + 1);
    }

    // ---- rowmin partial emission (once per block; plain stores) ----
    #pragma unroll
    for (int rt = 0; rt < 4; rt++)
        #pragma unroll
        for (int i = 0; i < 4; i++) {
            float v = rmin[rt][i];
            #pragma unroll
            for (int m = 1; m < 16; m <<= 1) v = fminf(v, __shfl_xor(v, m));
            if (l16 == 0) {
                // clamp commutes with the later min over jc (monotone)
                rpart[rpb + rowBase + rt * 16 + quad * 4 + i] =
                    fminf(fmaxf(x2v[rt][i] + v, 0.0f), 100.0f);
            }
        }
}

// ---------------------------------------------------------------------------
// Kernel 3a: reduce partials. 64 blocks x 256 threads; element e = thread.
//   rowmin: min over 16 jc slices of rpart (already clamped).
//   colmin: min over 64 (iT,wave) slices of cpart, + y2, clamp.
// All reads coalesced (consecutive threads -> consecutive elements/slice).
// ---------------------------------------------------------------------------
__global__ __launch_bounds__(256) void finalize1_kernel(
    const float* __restrict__ rpart, const float* __restrict__ cpart,
    const float* __restrict__ y2, float* __restrict__ partial)
{
    const int e = blockIdx.x * 256 + threadIdx.x;   // 0..16383
    const int b = e >> 12, i = e & (N_ - 1);

    float rm = 3.0e38f;
    #pragma unroll
    for (int j = 0; j < 16; j++)
        rm = fminf(rm, rpart[(size_t)(b * 16 + j) * N_ + i]);

    float cm = 3.0e38f;
    #pragma unroll
    for (int p = 0; p < 64; p++)
        cm = fminf(cm, cpart[(size_t)(b * 64 + p) * N_ + i]);

    float s = rm + fminf(fmaxf(cm + y2[e], 0.0f), 100.0f);

    #pragma unroll
    for (int m = 1; m < 64; m <<= 1) s += __shfl_xor(s, m);
    __shared__ float sm[4];
    if ((threadIdx.x & 63) == 0) sm[threadIdx.x >> 6] = s;
    __syncthreads();
    if (threadIdx.x == 0)
        partial[blockIdx.x] = sm[0] + sm[1] + sm[2] + sm[3];
}

// Kernel 3b: one wave folds the 64 partials.
__global__ __launch_bounds__(64) void finalize2_kernel(
    const float* __restrict__ partial, float* __restrict__ out)
{
    const int l = threadIdx.x;
    float s = partial[l];
    #pragma unroll
    for (int m = 1; m < 64; m <<= 1) s += __shfl_xor(s, m);
    if (l == 0)
        out[0] = s / ((float)B_ * (float)N_) / (float)B_;
}

extern "C" void kernel_launch(void* const* d_in, const int* in_sizes, int n_in,
                              void* d_out, int out_size, void* d_ws, size_t ws_size,
                              hipStream_t stream) {
    const float* X = (const float*)d_in[0];   // corr_pred   [B,N,D] fp32
    const float* Y = (const float*)d_in[1];   // corr_target [B,N,D] fp32

    char* ws = (char*)d_ws;
    const size_t f8_bytes = (size_t)B_ * N_ * D_;       // 2 MB each (packed fp8)
    unsigned char* Xb = (unsigned char*)ws;
    unsigned char* Yb = (unsigned char*)(ws + f8_bytes);
    char* ws2 = ws + 2 * f8_bytes;
    const size_t vec_bytes = (size_t)B_ * N_ * 4;       // 64 KB each
    float* x2      = (float*)(ws2);
    float* y2      = (float*)(ws2 + vec_bytes);
    float* rpart   = (float*)(ws2 + 2 * vec_bytes);               // 1 MB
    float* cpart   = (float*)(ws2 + 2 * vec_bytes + 16 * vec_bytes);  // 4 MB
    float* partial = (float*)(ws2 + 2 * vec_bytes + 80 * vec_bytes);  // 64 floats
    float* out = (float*)d_out;

    prep_kernel<<<dim3(B_ * N_ / 16, 2), 256, 0, stream>>>(
        X, Y, Xb, Yb, x2, y2);
    chamfer_mfma<<<dim3(16, N_ / 256, B_), 256, 0, stream>>>(
        Xb, Yb, x2, y2, rpart, cpart);
    finalize1_kernel<<<64, 256, 0, stream>>>(rpart, cpart, y2, partial);
    finalize2_kernel<<<1, 64, 0, stream>>>(partial, out);
}